// Round 13
// baseline (373.919 us; speedup 1.0000x reference)
//
#include <hip/hip_runtime.h>
#include <hip/hip_bf16.h>

// slotGATConv on MI355X.  R13:
//  - node_gather split into 3 sequential t-slice passes. A t-slice of an ft
//    row = 4 aligned 128B lines (floats h*96+t*32..+31). Per-pass ft
//    footprint 25.6MB -> forced L3 residency (R12: single-pass 76.8MB
//    thrashed, FETCH 345MB vs ~160 expected). Lane h=lg>>3 -> scalar
//    logit/exp/den per edge.
//  - rest unchanged from R12 (fused logits, packed u32 CSR, 2-phase scan,
//    unroll-8 transform).

#define NT 3
#define NH 4
#define DIN 64
#define DOUT 32
#define COLS 128   // NH*DOUT
#define FPN 384    // NT*COLS
#define TN 64      // nodes per block (node_transform)

typedef float vf4 __attribute__((ext_vector_type(4)));

__global__ void ee_table_kernel(const float* __restrict__ emb,
                                const float* __restrict__ fce,   // [256,64]
                                const float* __restrict__ attn_e,// [4*64]
                                float* __restrict__ ee_tab) {    // [5*4]
  const int lane = threadIdx.x;      // 64
  const int et = blockIdx.x >> 2;    // 0..4
  const int h  = blockIdx.x & 3;     // 0..3
  const float* w = fce + (size_t)(h * 64 + lane) * 64;
  const float* em = emb + et * 64;
  float dot = 0.f;
  #pragma unroll
  for (int k = 0; k < 64; ++k) dot = fmaf(em[k], w[k], dot);
  float v = dot * attn_e[h * 64 + lane];
  #pragma unroll
  for (int off = 32; off >= 1; off >>= 1) v += __shfl_xor(v, off);
  if (lane == 0) ee_tab[et * 4 + h] = v;
}

// 256 threads: cg = tid&31 (4 cols each -> 128 cols), ng = tid>>5 (8 nodes
// each -> 64 nodes). One t-slice per block (blockIdx.y).
__global__ __launch_bounds__(256, 4) void node_transform(
    const float* __restrict__ feat,   // [N,192]
    const float* __restrict__ fc,     // [3,64,128]
    const float* __restrict__ resw,   // [3,64,128]
    const float* __restrict__ attn_l, // [4*96]
    const float* __restrict__ attn_r, // [4*96]
    float* __restrict__ ft,           // [N,384]
    float* __restrict__ out,          // [N,384] <- resval
    float* __restrict__ el,           // [N,4] zeroed, atomic-accumulated
    float* __restrict__ er,           // [N,4] zeroed, atomic-accumulated
    int N) {
  __shared__ float hT[DIN][68];       // transposed h slice; pad 68 ->
                                      // conflict-free b128 reads (0 conf)
  const int t = blockIdx.y;
  const int tid = threadIdx.x;
  const int cg = tid & 31;            // col group: cols c0..c0+3
  const int ng = tid >> 5;            // node group: nodes nb..nb+7
  const int c0 = cg * 4;
  const int nb = ng * 8;
  const int head = c0 >> 5;           // 4 cols stay within one head
  const int o0 = c0 & 31;
  const int n0 = blockIdx.x * TN;

  {
    // stage hT: thread r=tid&63 loads 4 float4s of feat[n0+r][t*64+...]
    const int r = tid & 63;
    const int dq0 = tid >> 6;         // 0..3
    int n = n0 + r; if (n >= N) n = N - 1;
    const float* fp = feat + (size_t)n * (NT * DIN) + t * DIN;
    #pragma unroll
    for (int k = 0; k < 4; ++k) {
      const int d = (dq0 + k * 4) * 4;     // quads {dq0, dq0+4, dq0+8, dq0+12}
      const float4 v = *(const float4*)(fp + d);
      hT[d + 0][r] = v.x;
      hT[d + 1][r] = v.y;
      hT[d + 2][r] = v.z;
      hT[d + 3][r] = v.w;
    }
  }
  __syncthreads();

  float accF[8][4], accR[8][4];
  #pragma unroll
  for (int i = 0; i < 8; ++i)
    #pragma unroll
    for (int j = 0; j < 4; ++j) { accF[i][j] = 0.f; accR[i][j] = 0.f; }

  const float* wfp = fc + (size_t)t * DIN * COLS + c0;
  const float* wrp = resw + (size_t)t * DIN * COLS + c0;

  #pragma unroll 8
  for (int d = 0; d < DIN; ++d) {
    const float4 h0 = *(const float4*)&hT[d][nb];
    const float4 h1 = *(const float4*)&hT[d][nb + 4];
    const float4 wA = *(const float4*)(wfp + (size_t)d * COLS);
    const float4 wB = *(const float4*)(wrp + (size_t)d * COLS);
    const float hv[8] = {h0.x, h0.y, h0.z, h0.w, h1.x, h1.y, h1.z, h1.w};
    const float wa[4] = {wA.x, wA.y, wA.z, wA.w};
    const float wb[4] = {wB.x, wB.y, wB.z, wB.w};
    #pragma unroll
    for (int i = 0; i < 8; ++i)
      #pragma unroll
      for (int j = 0; j < 4; ++j) {
        accF[i][j] = fmaf(hv[i], wa[j], accF[i][j]);
        accR[i][j] = fmaf(hv[i], wb[j], accR[i][j]);
      }
  }

  // epilogue: store ft/resval slice, partial el/er -> shfl reduce -> atomic
  const float4 al4 = *(const float4*)(attn_l + head * 96 + t * 32 + o0);
  const float4 ar4 = *(const float4*)(attn_r + head * 96 + t * 32 + o0);
  const float al[4] = {al4.x, al4.y, al4.z, al4.w};
  const float ar[4] = {ar4.x, ar4.y, ar4.z, ar4.w};
  #pragma unroll
  for (int i = 0; i < 8; ++i) {
    const int n = n0 + nb + i;
    float s1 = 0.f, s2 = 0.f;
    #pragma unroll
    for (int j = 0; j < 4; ++j) {
      s1 = fmaf(accF[i][j], al[j], s1);
      s2 = fmaf(accF[i][j], ar[j], s2);
    }
    if (n < N) {
      const size_t oidx = (size_t)n * FPN + head * 96 + t * 32 + o0;
      *(float4*)(ft + oidx)  = make_float4(accF[i][0], accF[i][1],
                                           accF[i][2], accF[i][3]);
      *(float4*)(out + oidx) = make_float4(accR[i][0], accR[i][1],
                                           accR[i][2], accR[i][3]);
    }
    // reduce over the 8 col-groups of this head (consecutive lanes, 8-aligned)
    #pragma unroll
    for (int off = 1; off <= 4; off <<= 1) {
      s1 += __shfl_xor(s1, off);
      s2 += __shfl_xor(s2, off);
    }
    if ((cg & 7) == 0 && n < N) {
      atomicAdd(&el[n * 4 + head], s1);
      atomicAdd(&er[n * 4 + head], s2);
    }
  }
}

__global__ void deg_count(const int* __restrict__ dst,
                          int* __restrict__ deg, int E) {
  int eid = blockIdx.x * 256 + threadIdx.x;
  if (eid >= E) return;
  atomicAdd(&deg[dst[eid]], 1);
}

// ---- 2-phase multi-block exclusive scan ----
__global__ __launch_bounds__(256) void scan_partial(const int* __restrict__ deg,
                                                    int* __restrict__ partial,
                                                    int N) {
  __shared__ int sh[256];
  const int tid = threadIdx.x;
  const int i = blockIdx.x * 256 + tid;
  sh[tid] = (i < N) ? deg[i] : 0;
  __syncthreads();
  #pragma unroll
  for (int off = 128; off >= 1; off >>= 1) {
    if (tid < off) sh[tid] += sh[tid + off];
    __syncthreads();
  }
  if (tid == 0) partial[blockIdx.x] = sh[0];
}

// scan_apply derives its block base from partial[] (no scan_root)
__global__ __launch_bounds__(256) void scan_apply(const int* __restrict__ deg,
                                                  const int* __restrict__ partial,
                                                  int* __restrict__ offsets,
                                                  int* __restrict__ cursor,
                                                  int N) {
  __shared__ int sh[256];
  __shared__ int base_s;
  const int tid = threadIdx.x;

  // block base = sum of partial[0 .. blockIdx.x-1]
  int b = 0;
  for (int i = tid; i < blockIdx.x; i += 256) b += partial[i];
  sh[tid] = b;
  __syncthreads();
  #pragma unroll
  for (int off = 128; off >= 1; off >>= 1) {
    if (tid < off) sh[tid] += sh[tid + off];
    __syncthreads();
  }
  if (tid == 0) base_s = sh[0];
  __syncthreads();

  // local inclusive scan of this block's 256 deg values
  const int i = blockIdx.x * 256 + tid;
  const int v = (i < N) ? deg[i] : 0;
  sh[tid] = v;
  __syncthreads();
  #pragma unroll
  for (int off = 1; off < 256; off <<= 1) {
    const int add = (tid >= off) ? sh[tid - off] : 0;
    __syncthreads();
    sh[tid] += add;
    __syncthreads();
  }
  const int excl = sh[tid] - v + base_s;
  if (i < N) { offsets[i] = excl; cursor[i] = excl; }
  if (i == N - 1) offsets[N] = excl + v;   // total E
}

// CSR fill: packed u32 record {et:3 | src:17} per edge (src < 2^17, et < 5)
__global__ void csr_fill(const int* __restrict__ e_feat,
                         const int* __restrict__ src,
                         const int* __restrict__ dst,
                         int* __restrict__ cursor,
                         unsigned* __restrict__ csr,
                         int E) {
  int eid = blockIdx.x * 256 + threadIdx.x;
  if (eid >= E) return;
  int d = dst[eid];
  int pos = atomicAdd(&cursor[d], 1);
  csr[pos] = (unsigned)src[eid] | ((unsigned)e_feat[eid] << 17);
}

// One t-slice per dispatch. 32-lane group per node, 8 nodes/block.
// Lane lg: head h = lg>>3, float4 q = lg&7 -> row float4 index
// h*24 + t*8 + q (the slice's 4 aligned 128B lines). Scalar logit/exp/den.
__global__ __launch_bounds__(256) void node_gather_slice(
    const int* __restrict__ offsets,
    const unsigned* __restrict__ csr,
    const float* __restrict__ el,      // [N,4]
    const float* __restrict__ er,      // [N,4]
    const float* __restrict__ ee_tab,  // [5,4]
    const float* __restrict__ ft,      // [N,384]
    float* __restrict__ out,           // [N,384] += sum(ex*ft)/den
    int N, int t) {
  __shared__ float see[20];
  if (threadIdx.x < 20) see[threadIdx.x] = ee_tab[threadIdx.x];
  __syncthreads();

  const int g  = threadIdx.x >> 5;     // node group in block
  const int lg = threadIdx.x & 31;     // lane in group
  const int n = blockIdx.x * 8 + g;
  if (n >= N) return;
  const int beg = offsets[n], end = offsets[n + 1];
  if (beg == end) return;              // out keeps resval

  const int h = lg >> 3;               // this lane's head
  const int q = lg & 7;                // float4 within the head's t-chunk
  const int f4 = h * 24 + t * 8 + q;   // float4 index within the row
  const float er_h = er[(size_t)n * 4 + h];

  vf4 acc = (vf4)0.f;
  float den = 0.f;

  auto edge_ex = [&](unsigned rec, int& s_out) -> float {
    const int s = rec & 0x1FFFF;
    const int et = rec >> 17;
    s_out = s;
    float e = el[(size_t)s * 4 + h] + er_h + see[et * 4 + h];
    e = (e >= 0.f) ? e : 0.2f * e;
    // no max-subtraction: |e| small, f32 exp overflow-safe; exp(e)/sum
    // identical to the ref's max-shifted form.
    return __expf(e);
  };

  int k = beg;
  for (; k + 1 < end; k += 2) {
    int s0, s1;
    const float x0 = edge_ex(csr[k], s0);
    const float x1 = edge_ex(csr[k + 1], s1);
    den += x0 + x1;
    const vf4 a = ((const vf4*)(ft + (size_t)s0 * FPN))[f4];
    const vf4 b = ((const vf4*)(ft + (size_t)s1 * FPN))[f4];
    #pragma unroll
    for (int u = 0; u < 4; ++u) {
      acc[u] = fmaf(a[u], x0, acc[u]);
      acc[u] = fmaf(b[u], x1, acc[u]);
    }
  }
  if (k < end) {
    int s0;
    const float x0 = edge_ex(csr[k], s0);
    den += x0;
    const vf4 a = ((const vf4*)(ft + (size_t)s0 * FPN))[f4];
    #pragma unroll
    for (int u = 0; u < 4; ++u)
      acc[u] = fmaf(a[u], x0, acc[u]);
  }

  const float iv = 1.0f / den;
  vf4* op = (vf4*)(out + (size_t)n * FPN);
  vf4 cur = op[f4];
  #pragma unroll
  for (int u = 0; u < 4; ++u)
    cur[u] = fmaf(acc[u], iv, cur[u]);
  op[f4] = cur;
}

extern "C" void kernel_launch(void* const* d_in, const int* in_sizes, int n_in,
                              void* d_out, int out_size, void* d_ws, size_t ws_size,
                              hipStream_t stream) {
  const float* feat   = (const float*)d_in[0];
  const int*   e_feat = (const int*)d_in[1];
  const int*   src    = (const int*)d_in[2];
  const int*   dst    = (const int*)d_in[3];
  const float* fc     = (const float*)d_in[4];
  const float* resw   = (const float*)d_in[5];
  const float* emb    = (const float*)d_in[6];
  const float* fce    = (const float*)d_in[7];
  const float* attn_l = (const float*)d_in[8];
  const float* attn_r = (const float*)d_in[9];
  const float* attn_e = (const float*)d_in[10];

  const int N = in_sizes[0] / (NT * DIN);
  const int E = in_sizes[1];
  float* out = (float*)d_out;

  char* p = (char*)d_ws;
  auto carve = [&](size_t bytes) -> char* {
    char* r = p;
    p += (bytes + 255) & ~(size_t)255;
    return r;
  };
  float*    ft      = (float*)   carve((size_t)N * FPN * 4);
  char*     zbase   = p;                   // el, er, deg zeroed in one memset
  float*    el      = (float*)   carve((size_t)N * 4 * 4);
  float*    er      = (float*)   carve((size_t)N * 4 * 4);
  int*      deg     = (int*)     carve((size_t)N * 4);
  size_t    zbytes  = (size_t)(p - zbase);
  int*      offsets = (int*)     carve((size_t)(N + 1) * 4);
  int*      cursor  = (int*)     carve((size_t)N * 4);
  int*      partial = (int*)     carve(256 * 4);
  unsigned* csr     = (unsigned*)carve((size_t)E * 4);
  float*    ee_tab  = (float*)   carve(32 * 4);

  const int nscan = (N + 255) / 256;

  (void)hipMemsetAsync(zbase, 0, zbytes, stream);
  ee_table_kernel<<<20, 64, 0, stream>>>(emb, fce, attn_e, ee_tab);
  node_transform<<<dim3((N + TN - 1) / TN, NT), 256, 0, stream>>>(
      feat, fc, resw, attn_l, attn_r, ft, out, el, er, N);
  deg_count<<<(E + 255) / 256, 256, 0, stream>>>(dst, deg, E);
  scan_partial<<<nscan, 256, 0, stream>>>(deg, partial, N);
  scan_apply<<<nscan, 256, 0, stream>>>(deg, partial, offsets, cursor, N);
  csr_fill<<<(E + 255) / 256, 256, 0, stream>>>(
      e_feat, src, dst, cursor, csr, E);
  for (int t = 0; t < NT; ++t)
    node_gather_slice<<<(N + 7) / 8, 256, 0, stream>>>(
        offsets, csr, el, er, ee_tab, ft, out, N, t);
}